// Round 3
// baseline (320.448 us; speedup 1.0000x reference)
//
#include <hip/hip_runtime.h>
#include <hip/hip_bf16.h>
#include <math.h>

#define H 256
#define F 512
#define E 8
#define T_TOK 32768
#define BM 128   // tokens per block
#define FC 64    // F-chunk size
#define NCH 64   // E * (F/FC) total chunk-stages

typedef float    f32x4 __attribute__((__ext_vector_type__(4)));
typedef _Float16 f16x8 __attribute__((__ext_vector_type__(8)));
typedef _Float16 f16x4 __attribute__((__ext_vector_type__(4)));

#define BAR_LG()  asm volatile("s_waitcnt lgkmcnt(0)\ns_barrier" ::: "memory")
#define BAR_ALL() asm volatile("s_waitcnt vmcnt(0) lgkmcnt(0)\ns_barrier" ::: "memory")

__device__ __forceinline__ void async_copy16(const void* g, void* l) {
    __builtin_amdgcn_global_load_lds((const __attribute__((address_space(1))) void*)g,
                                     (__attribute__((address_space(3))) void*)l, 16, 0, 0);
}

__device__ __forceinline__ float gelu_fast(float v) {
    // tanh-approx GELU: max |err| vs erf-GELU ~5e-4, hardware exp+rcp
    float u = 0.7978845608028654f * v * (1.0f + 0.044715f * v * v);
    float ex = __expf(2.0f * u);
    float t = 1.0f - 2.0f * __builtin_amdgcn_rcpf(ex + 1.0f);
    return 0.5f * v * (1.0f + t);
}

// ---- transpose + convert: per expert, in fp32 [R][C] -> out fp16 [C][R]
__global__ void transpose_cvt(const float* __restrict__ in, _Float16* __restrict__ out,
                              int R, int C) {
    __shared__ float tile[32][33];
    int e = blockIdx.z;
    const float* inp = in + (size_t)e * R * C;
    _Float16* outp = out + (size_t)e * R * C;
    int c0 = blockIdx.x * 32, r0 = blockIdx.y * 32;
    int tx = threadIdx.x, ty = threadIdx.y; // 32 x 8
    for (int i = 0; i < 32; i += 8)
        tile[ty + i][tx] = inp[(size_t)(r0 + ty + i) * C + c0 + tx];
    __syncthreads();
    for (int i = 0; i < 32; i += 8)
        outp[(size_t)(c0 + ty + i) * R + r0 + tx] = (_Float16)tile[tx][ty + i];
}

// ---- gate: probs = softmax(x @ Wg + bg) over E; 8 threads per token
__global__ void gate_kernel(const float* __restrict__ x, const float* __restrict__ Wg,
                            const float* __restrict__ bg, float* __restrict__ probs) {
    int gid = blockIdx.x * blockDim.x + threadIdx.x;
    int t = gid >> 3, e = gid & 7;
    const float* xr = x + (size_t)t * H;
    float acc = 0.f;
    for (int k = 0; k < H; k += 4) {
        float4 xv = *(const float4*)(xr + k);
        acc += xv.x * Wg[(k + 0) * E + e] + xv.y * Wg[(k + 1) * E + e]
             + xv.z * Wg[(k + 2) * E + e] + xv.w * Wg[(k + 3) * E + e];
    }
    acc += bg[e];
    float m = acc;
    for (int s = 1; s < 8; s <<= 1) m = fmaxf(m, __shfl_xor(m, s, 8));
    float p = expf(acc - m);
    float sum = p;
    for (int s = 1; s < 8; s <<= 1) sum += __shfl_xor(sum, s, 8);
    probs[gid] = p / sum;
}

// stage chunk s's W1 tile into LDS (async, 16B): linear LDS dest,
// pre-swizzled global source (byte ^ ((row&7)<<4), row = 512B of H fp16)
__device__ __forceinline__ void stage_w1(const _Float16* W1t, int s, _Float16* w1d,
                                         int wid, int lane) {
    int e = s >> 3, cc = s & 7, fbase = cc * FC;
    const char* W1c = (const char*)(W1t + (size_t)e * F * H + (size_t)fbase * H);
#pragma unroll
    for (int q = 0; q < 4; ++q) {
        int seg = wid * 4 + q;             // 0..31, wave-uniform
        int o = seg * 1024 + lane * 16;    // linear byte offset in the 32KB tile
        int r1 = o >> 9;
        async_copy16(W1c + (o ^ ((r1 & 7) << 4)), (char*)w1d + seg * 1024);
    }
}

// ---- main fused MoE FFN
__global__ __launch_bounds__(512, 2) void moe_main(
    const float* __restrict__ x, const _Float16* __restrict__ W1t,
    const float* __restrict__ b1, const _Float16* __restrict__ W2t,
    const float* __restrict__ b2, const float* __restrict__ probs,
    float* __restrict__ out) {

    __shared__ __align__(16) _Float16 w1s[2][FC * H];  // 2 x 32 KB
    __shared__ __align__(16) _Float16 hs[BM * FC];     // 16 KB

    int tid = threadIdx.x;
    int lane = tid & 63, wid = tid >> 6;
    int t0 = blockIdx.x * BM;
    int l15 = lane & 15, l4 = lane >> 4;

    // wave coords
    int fw = wid >> 2, tw1 = wid & 3;   // GEMM1: 2(f) x 4(tok), 2x2 16-tiles each
    int hw = wid >> 1, tw2 = wid & 1;   // GEMM2: 4(h) x 2(tok), 4x4 16-tiles each

    // x B-fragments in registers, loaded once, reused for all 64 chunk-stages.
    f16x8 xf[8][2];
#pragma unroll
    for (int j = 0; j < 2; ++j) {
        const float* xr = x + (size_t)(t0 + tw1 * 32 + j * 16 + l15) * H + (l4 << 3);
#pragma unroll
        for (int ks = 0; ks < 8; ++ks) {
            const float4* gp = (const float4*)(xr + ks * 32);
            float4 v0 = gp[0], v1 = gp[1];
            f16x8 hv;
            hv[0] = (_Float16)v0.x; hv[1] = (_Float16)v0.y; hv[2] = (_Float16)v0.z; hv[3] = (_Float16)v0.w;
            hv[4] = (_Float16)v1.x; hv[5] = (_Float16)v1.y; hv[6] = (_Float16)v1.z; hv[7] = (_Float16)v1.w;
            xf[ks][j] = hv;
        }
    }

    // prologue: stage chunk 0 into buf 0
    stage_w1(W1t, 0, w1s[0], wid, lane);
    BAR_ALL();

    f32x4 yacc[4][4];
#pragma unroll
    for (int i = 0; i < 4; ++i)
#pragma unroll
        for (int j = 0; j < 4; ++j) yacc[i][j] = (f32x4){0.f, 0.f, 0.f, 0.f};

    for (int e = 0; e < E; ++e) {
        const _Float16* W2e = W2t + (size_t)e * H * F;
        float pg0 = probs[(size_t)(t0 + tw1 * 32 + l15) * E + e];
        float pg1 = probs[(size_t)(t0 + tw1 * 32 + 16 + l15) * E + e];

        for (int c = 0; c < F / FC; ++c) {
            int s = e * 8 + c;
            int b = s & 1;
            int fbase = c * FC;
            const _Float16* w1p = w1s[b];

            // (1) issue W2 A-fragment loads for THIS chunk (global, L2-resident).
            //     Issued FIRST so vmcnt-wait for them doesn't drain the W1 prefetch.
            f16x8 av[4][2];
#pragma unroll
            for (int i = 0; i < 4; ++i) {
                int hr = hw * 64 + i * 16 + l15;
                const _Float16* wp = W2e + (size_t)hr * F + fbase + (l4 << 3);
                av[i][0] = *(const f16x8*)(wp);
                av[i][1] = *(const f16x8*)(wp + 32);
            }

            // (2) prefetch next chunk's W1 into the other buffer (in flight until BAR_ALL)
            if (s + 1 < NCH)
                stage_w1(W1t, s + 1, w1s[b ^ 1], wid, lane);

            // (3) GEMM1: hT[f][tok] = W1chunk . x^T, K=H  (x from registers)
            f32x4 hacc[2][2];
            hacc[0][0] = hacc[0][1] = hacc[1][0] = hacc[1][1] = (f32x4){0.f, 0.f, 0.f, 0.f};
            __builtin_amdgcn_s_setprio(1);
#pragma unroll
            for (int ks = 0; ks < 8; ++ks) {
                int kidx = ks * 32 + (l4 << 3);
                int fr0 = fw * 32 + l15, fr1 = fr0 + 16;
                f16x8 a0 = *(const f16x8*)&w1p[(fr0 * H + kidx) ^ ((fr0 & 7) << 3)];
                f16x8 a1 = *(const f16x8*)&w1p[(fr1 * H + kidx) ^ ((fr1 & 7) << 3)];
                hacc[0][0] = __builtin_amdgcn_mfma_f32_16x16x32_f16(a0, xf[ks][0], hacc[0][0], 0, 0, 0);
                hacc[0][1] = __builtin_amdgcn_mfma_f32_16x16x32_f16(a0, xf[ks][1], hacc[0][1], 0, 0, 0);
                hacc[1][0] = __builtin_amdgcn_mfma_f32_16x16x32_f16(a1, xf[ks][0], hacc[1][0], 0, 0, 0);
                hacc[1][1] = __builtin_amdgcn_mfma_f32_16x16x32_f16(a1, xf[ks][1], hacc[1][1], 0, 0, 0);
            }
            __builtin_amdgcn_s_setprio(0);

            // (4) epilogue: hs = p * gelu(h + b1)
#pragma unroll
            for (int i = 0; i < 2; ++i) {
                int flocal = (fw * 2 + i) * 16 + l4 * 4;
                float4 bv = *(const float4*)(b1 + (size_t)e * F + fbase + flocal);
#pragma unroll
                for (int j = 0; j < 2; ++j) {
                    int tokl = tw1 * 32 + j * 16 + l15;
                    float p = j ? pg1 : pg0;
                    f32x4 hv = hacc[i][j];
                    f16x4 hp;
                    hp[0] = (_Float16)(p * gelu_fast(hv[0] + bv.x));
                    hp[1] = (_Float16)(p * gelu_fast(hv[1] + bv.y));
                    hp[2] = (_Float16)(p * gelu_fast(hv[2] + bv.z));
                    hp[3] = (_Float16)(p * gelu_fast(hv[3] + bv.w));
                    int idx = (tokl * FC + flocal) ^ ((tokl & 7) << 3);
                    *(f16x4*)&hs[idx] = hp;
                }
            }
            BAR_LG();  // hs ready; W1 prefetch stays in flight

            // (5) GEMM2: y[h][tok] += W2chunk . hs^T, K=FC (av from registers)
            __builtin_amdgcn_s_setprio(1);
#pragma unroll
            for (int ks = 0; ks < FC / 32; ++ks) {
                int kidx = ks * 32 + (l4 << 3);
                f16x8 bv2[4];
#pragma unroll
                for (int j = 0; j < 4; ++j) {
                    int tok = tw2 * 64 + j * 16 + l15;
                    bv2[j] = *(const f16x8*)&hs[(tok * FC + kidx) ^ ((tok & 7) << 3)];
                }
#pragma unroll
                for (int i = 0; i < 4; ++i)
#pragma unroll
                    for (int j = 0; j < 4; ++j)
                        yacc[i][j] = __builtin_amdgcn_mfma_f32_16x16x32_f16(av[i][ks], bv2[j], yacc[i][j], 0, 0, 0);
            }
            __builtin_amdgcn_s_setprio(0);
            BAR_ALL();  // GEMM2 hs reads done + next chunk's W1 staging landed
        } // chunk loop
    } // expert loop

    // epilogue: out = yacc + sum_e p_e * b2_e ; write fp32
#pragma unroll
    for (int j = 0; j < 4; ++j) {
        int tok = t0 + tw2 * 64 + j * 16 + l15;
        for (int e = 0; e < 8; ++e) {
            float pe = probs[(size_t)tok * E + e];
#pragma unroll
            for (int i = 0; i < 4; ++i) {
                int h0 = hw * 64 + i * 16 + l4 * 4;
                float4 b2v = *(const float4*)(b2 + (size_t)e * H + h0);
                yacc[i][j][0] += pe * b2v.x;
                yacc[i][j][1] += pe * b2v.y;
                yacc[i][j][2] += pe * b2v.z;
                yacc[i][j][3] += pe * b2v.w;
            }
        }
#pragma unroll
        for (int i = 0; i < 4; ++i) {
            int h0 = hw * 64 + i * 16 + l4 * 4;
            *(f32x4*)(out + (size_t)tok * H + h0) = yacc[i][j];
        }
    }
}

extern "C" void kernel_launch(void* const* d_in, const int* in_sizes, int n_in,
                              void* d_out, int out_size, void* d_ws, size_t ws_size,
                              hipStream_t stream) {
    const float* x  = (const float*)d_in[0];
    const float* Wg = (const float*)d_in[1];
    const float* bg = (const float*)d_in[2];
    const float* W1 = (const float*)d_in[3];
    const float* b1 = (const float*)d_in[4];
    const float* W2 = (const float*)d_in[5];
    const float* b2 = (const float*)d_in[6];
    float* out = (float*)d_out;

    _Float16* W1t = (_Float16*)d_ws;                       // [E][F][H] fp16, 2 MB
    _Float16* W2t = W1t + (size_t)E * F * H;               // [E][H][F] fp16, 2 MB
    float* probs  = (float*)(W2t + (size_t)E * H * F);     // [T][E] fp32, 1 MB

    dim3 tb(32, 8);
    transpose_cvt<<<dim3(F / 32, H / 32, E), tb, 0, stream>>>(W1, W1t, H, F);
    transpose_cvt<<<dim3(H / 32, F / 32, E), tb, 0, stream>>>(W2, W2t, F, H);
    gate_kernel<<<(T_TOK * E) / 256, 256, 0, stream>>>(x, Wg, bg, probs);
    moe_main<<<T_TOK / BM, 512, 0, stream>>>(x, W1t, b1, W2t, b2, probs, out);
}

// Round 4
// 291.370 us; speedup vs baseline: 1.0998x; 1.0998x over previous
//
#include <hip/hip_runtime.h>
#include <hip/hip_bf16.h>
#include <math.h>

#define H 256
#define F 512
#define E 8
#define T_TOK 32768
#define BM 128   // tokens per block
#define FC 32    // F-chunk (GEMM K-slice per stage)
#define NCH 128  // E * F/FC total chunks

typedef float    f32x4 __attribute__((__ext_vector_type__(4)));
typedef _Float16 f16x8 __attribute__((__ext_vector_type__(8)));
typedef _Float16 f16x4 __attribute__((__ext_vector_type__(4)));

#define BAR_ALL() asm volatile("s_waitcnt vmcnt(0) lgkmcnt(0)\ns_barrier" ::: "memory")

__device__ __forceinline__ void async_copy16(const void* g, void* l) {
    __builtin_amdgcn_global_load_lds((const __attribute__((address_space(1))) void*)g,
                                     (__attribute__((address_space(3))) void*)l, 16, 0, 0);
}

__device__ __forceinline__ float gelu_fast(float v) {
    float u = 0.7978845608028654f * v * (1.0f + 0.044715f * v * v);
    float ex = __expf(2.0f * u);
    float t = 1.0f - 2.0f * __builtin_amdgcn_rcpf(ex + 1.0f);
    return 0.5f * v * (1.0f + t);
}

// W1[e][h][f] fp32 -> W1t[e][f][ h ^ ((f&7)<<3) ] fp16  (swizzle baked)
__global__ void prep_w1(const float* __restrict__ in, _Float16* __restrict__ out) {
    __shared__ float t[32][33];
    int e = blockIdx.z, f0 = blockIdx.x * 32, h0 = blockIdx.y * 32;
    int tx = threadIdx.x, ty = threadIdx.y;
    const float* ip = in + ((size_t)e * H + h0) * F + f0;
    for (int i = 0; i < 32; i += 8) t[ty + i][tx] = ip[(size_t)(ty + i) * F + tx]; // t[hl][fl]
    __syncthreads();
    _Float16* op = out + (size_t)e * F * H;
    for (int i = 0; i < 32; i += 8) {
        int f = f0 + ty + i, h = h0 + tx;
        op[(size_t)f * H + (h ^ ((f & 7) << 3))] = (_Float16)t[tx][ty + i];
    }
}

// W2[e][f][h] fp32 -> W2t[e][f>>6][h][ (f&63) ^ ((h&7)<<3) ] fp16  (64-f units, swizzle baked)
__global__ void prep_w2(const float* __restrict__ in, _Float16* __restrict__ out) {
    __shared__ float t[32][33];
    int e = blockIdx.z, h0 = blockIdx.x * 32, f0 = blockIdx.y * 32;
    int tx = threadIdx.x, ty = threadIdx.y;
    const float* ip = in + ((size_t)e * F + f0) * H + h0;
    for (int i = 0; i < 32; i += 8) t[ty + i][tx] = ip[(size_t)(ty + i) * H + tx]; // t[fl][hl]
    __syncthreads();
    _Float16* op = out + (size_t)e * 8 * 256 * 64;
    for (int i = 0; i < 32; i += 8) {
        int h = h0 + ty + i, f = f0 + tx;
        op[((size_t)(f >> 6) * 256 + h) * 64 + ((f & 63) ^ ((h & 7) << 3))] = (_Float16)t[tx][ty + i];
    }
}

__global__ void gate_kernel(const float* __restrict__ x, const float* __restrict__ Wg,
                            const float* __restrict__ bg, float* __restrict__ probs) {
    int gid = blockIdx.x * blockDim.x + threadIdx.x;
    int t = gid >> 3, e = gid & 7;
    const float* xr = x + (size_t)t * H;
    float acc = 0.f;
    for (int k = 0; k < H; k += 4) {
        float4 xv = *(const float4*)(xr + k);
        acc += xv.x * Wg[(k + 0) * E + e] + xv.y * Wg[(k + 1) * E + e]
             + xv.z * Wg[(k + 2) * E + e] + xv.w * Wg[(k + 3) * E + e];
    }
    acc += bg[e];
    float m = acc;
    for (int s = 1; s < 8; s <<= 1) m = fmaxf(m, __shfl_xor(m, s, 8));
    float p = expf(acc - m);
    float sum = p;
    for (int s = 1; s < 8; s <<= 1) sum += __shfl_xor(sum, s, 8);
    probs[gid] = p / sum;
}

// ---- main fused MoE FFN: 4 producer waves (GEMM1+GELU) + 4 consumer waves (GEMM2)
__global__ __launch_bounds__(512, 2) void moe_main(
    const float* __restrict__ x, const _Float16* __restrict__ W1t,
    const float* __restrict__ b1, const _Float16* __restrict__ W2t,
    const float* __restrict__ b2, const float* __restrict__ probs,
    float* __restrict__ out) {

    __shared__ __align__(16) _Float16 w1s[2][FC * H];   // 2 x 16 KB
    __shared__ __align__(16) _Float16 w2s[3][H * 64];   // 3 x 32 KB (64-f units)
    __shared__ __align__(16) _Float16 hs[BM * 64];      // 16 KB, column-half = chunk parity

    const int tid = threadIdx.x, lane = tid & 63, wid = tid >> 6;
    const int t0 = blockIdx.x * BM;
    const int l15 = lane & 15, l4 = lane >> 4;

    // prologue: stage w1 chunk0 (16 segs) + w2 unit0 (32 segs); 6 segs/wave
    {
        const char* w1src = (const char*)W1t;
        const char* w2src = (const char*)W2t;
#pragma unroll
        for (int q = 0; q < 6; ++q) {
            int g = wid * 6 + q;
            if (g < 16) async_copy16(w1src + g * 1024 + lane * 16, (char*)w1s[0] + g * 1024);
            else        async_copy16(w2src + (g - 16) * 1024 + lane * 16, (char*)w2s[0] + (g - 16) * 1024);
        }
    }
    BAR_ALL();

    if (wid < 4) {
        // ================= PRODUCER =================
        const int fhalf = wid >> 1, twp = wid & 1;
        // x-file: xf[ks][j] = x[t0+twp*64+j*16+l15][ks*32+l4*8 .. +8]
        f16x8 xf[8][4];
#pragma unroll
        for (int j = 0; j < 4; ++j) {
            const float* xr = x + (size_t)(t0 + twp * 64 + j * 16 + l15) * H + l4 * 8;
#pragma unroll
            for (int ks = 0; ks < 8; ++ks) {
                float4 v0 = *(const float4*)(xr + ks * 32);
                float4 v1 = *(const float4*)(xr + ks * 32 + 4);
                f16x8 hv;
                hv[0] = (_Float16)v0.x; hv[1] = (_Float16)v0.y; hv[2] = (_Float16)v0.z; hv[3] = (_Float16)v0.w;
                hv[4] = (_Float16)v1.x; hv[5] = (_Float16)v1.y; hv[6] = (_Float16)v1.z; hv[7] = (_Float16)v1.w;
                xf[ks][j] = hv;
            }
        }
        float pg[4];
        const int fl = fhalf * 16 + l15;
        const int rowbase = fl * H;
        const int swz = (fl & 7) << 3;

        for (int s = 0; s < NCH; ++s) {
            int b = s & 1;
            // stage w1 chunk s+1 (16 segs / 4 producer waves)
            if (s + 1 < NCH) {
                const char* src = (const char*)(W1t + (size_t)(s + 1) * FC * H);
                char* dst = (char*)w1s[(s + 1) & 1];
#pragma unroll
                for (int q = 0; q < 4; ++q) {
                    int seg = wid * 4 + q;
                    async_copy16(src + seg * 1024 + lane * 16, dst + seg * 1024);
                }
            }
            int e = s >> 4, c16 = s & 15;
            if (c16 == 0) {
#pragma unroll
                for (int j = 0; j < 4; ++j)
                    pg[j] = probs[(size_t)(t0 + twp * 64 + j * 16 + l15) * E + e];
            }
            // GEMM1: h[fl][tok 64] , K=H from x-regs
            f32x4 hacc[4];
            hacc[0] = hacc[1] = hacc[2] = hacc[3] = (f32x4){0.f, 0.f, 0.f, 0.f};
            const _Float16* w1p = w1s[b];
            __builtin_amdgcn_s_setprio(1);
#pragma unroll
            for (int ks = 0; ks < 8; ++ks) {
                f16x8 a = *(const f16x8*)&w1p[rowbase + ((ks * 32 + l4 * 8) ^ swz)];
                hacc[0] = __builtin_amdgcn_mfma_f32_16x16x32_f16(a, xf[ks][0], hacc[0], 0, 0, 0);
                hacc[1] = __builtin_amdgcn_mfma_f32_16x16x32_f16(a, xf[ks][1], hacc[1], 0, 0, 0);
                hacc[2] = __builtin_amdgcn_mfma_f32_16x16x32_f16(a, xf[ks][2], hacc[2], 0, 0, 0);
                hacc[3] = __builtin_amdgcn_mfma_f32_16x16x32_f16(a, xf[ks][3], hacc[3], 0, 0, 0);
            }
            __builtin_amdgcn_s_setprio(0);
            // epilogue: hs[tok][(s&1)*32 + fhalf*16 + l4*4] = p * gelu(h + b1)
            int fb = c16 * 32 + fhalf * 16 + l4 * 4;
            float4 bv = *(const float4*)(b1 + (size_t)e * F + fb);
#pragma unroll
            for (int j = 0; j < 4; ++j) {
                int tokl = twp * 64 + j * 16 + l15;
                float p = pg[j];
                f16x4 hp;
                hp[0] = (_Float16)(p * gelu_fast(hacc[j][0] + bv.x));
                hp[1] = (_Float16)(p * gelu_fast(hacc[j][1] + bv.y));
                hp[2] = (_Float16)(p * gelu_fast(hacc[j][2] + bv.z));
                hp[3] = (_Float16)(p * gelu_fast(hacc[j][3] + bv.w));
                int colbyte = ((b * 32 + fhalf * 16 + l4 * 4) * 2) ^ ((tokl & 7) << 4);
                *(f16x4*)((char*)hs + tokl * 128 + colbyte) = hp;
            }
            BAR_ALL();
        }
    } else {
        // ================= CONSUMER =================
        const int cw = wid - 4, hwc = cw >> 1, twc = cw & 1;
        f32x4 yacc[8][4];
#pragma unroll
        for (int i = 0; i < 8; ++i)
#pragma unroll
            for (int j = 0; j < 4; ++j) yacc[i][j] = (f32x4){0.f, 0.f, 0.f, 0.f};

        for (int s = 0; s < NCH; ++s) {
            // stage w2: half (s&1) of unit (s>>1)+1 (16 segs / 4 consumer waves)
            int un = (s >> 1) + 1;
            if (un < 64) {
                const char* src = (const char*)(W2t + ((size_t)un * 256 + (size_t)(s & 1) * 128) * 64);
                char* dst = (char*)w2s[un % 3] + (s & 1) * 16384;
#pragma unroll
                for (int q = 0; q < 4; ++q) {
                    int seg = cw * 4 + q;
                    async_copy16(src + seg * 1024 + lane * 16, dst + seg * 1024);
                }
            }
            if (s > 0) {
                int sc = s - 1, khalf = sc & 1;
                const _Float16* w2p = w2s[(sc >> 1) % 3];
                int kb = khalf * 64 + l4 * 16;  // byte offset in 128B row
                f16x8 av[8], bvf[4];
#pragma unroll
                for (int i = 0; i < 8; ++i) {
                    int h = hwc * 128 + i * 16 + l15;
                    av[i] = *(const f16x8*)((const char*)w2p + h * 128 + (kb ^ ((h & 7) << 4)));
                }
#pragma unroll
                for (int j = 0; j < 4; ++j) {
                    int tk = twc * 64 + j * 16 + l15;
                    bvf[j] = *(const f16x8*)((const char*)hs + tk * 128 + (kb ^ ((tk & 7) << 4)));
                }
                __builtin_amdgcn_s_setprio(1);
#pragma unroll
                for (int i = 0; i < 8; ++i)
#pragma unroll
                    for (int j = 0; j < 4; ++j)
                        yacc[i][j] = __builtin_amdgcn_mfma_f32_16x16x32_f16(av[i], bvf[j], yacc[i][j], 0, 0, 0);
                __builtin_amdgcn_s_setprio(0);
            }
            BAR_ALL();
        }
        // final chunk (sc = NCH-1)
        {
            int sc = NCH - 1, khalf = sc & 1;
            const _Float16* w2p = w2s[(sc >> 1) % 3];
            int kb = khalf * 64 + l4 * 16;
            f16x8 av[8], bvf[4];
#pragma unroll
            for (int i = 0; i < 8; ++i) {
                int h = hwc * 128 + i * 16 + l15;
                av[i] = *(const f16x8*)((const char*)w2p + h * 128 + (kb ^ ((h & 7) << 4)));
            }
#pragma unroll
            for (int j = 0; j < 4; ++j) {
                int tk = twc * 64 + j * 16 + l15;
                bvf[j] = *(const f16x8*)((const char*)hs + tk * 128 + (kb ^ ((tk & 7) << 4)));
            }
#pragma unroll
            for (int i = 0; i < 8; ++i)
#pragma unroll
                for (int j = 0; j < 4; ++j)
                    yacc[i][j] = __builtin_amdgcn_mfma_f32_16x16x32_f16(av[i], bvf[j], yacc[i][j], 0, 0, 0);
        }
        // epilogue: out = yacc + sum_e p_e * b2_e
#pragma unroll
        for (int j = 0; j < 4; ++j) {
            int tok = t0 + twc * 64 + j * 16 + l15;
            float pe[8];
#pragma unroll
            for (int e = 0; e < 8; ++e) pe[e] = probs[(size_t)tok * E + e];
#pragma unroll
            for (int i = 0; i < 8; ++i) {
                int h0v = hwc * 128 + i * 16 + l4 * 4;
                f32x4 acc = yacc[i][j];
#pragma unroll
                for (int e = 0; e < 8; ++e) {
                    float4 b2v = *(const float4*)(b2 + (size_t)e * H + h0v);
                    acc[0] += pe[e] * b2v.x;
                    acc[1] += pe[e] * b2v.y;
                    acc[2] += pe[e] * b2v.z;
                    acc[3] += pe[e] * b2v.w;
                }
                *(f32x4*)(out + (size_t)tok * H + h0v) = acc;
            }
        }
    }
}

extern "C" void kernel_launch(void* const* d_in, const int* in_sizes, int n_in,
                              void* d_out, int out_size, void* d_ws, size_t ws_size,
                              hipStream_t stream) {
    const float* x  = (const float*)d_in[0];
    const float* Wg = (const float*)d_in[1];
    const float* bg = (const float*)d_in[2];
    const float* W1 = (const float*)d_in[3];
    const float* b1 = (const float*)d_in[4];
    const float* W2 = (const float*)d_in[5];
    const float* b2 = (const float*)d_in[6];
    float* out = (float*)d_out;

    _Float16* W1t = (_Float16*)d_ws;                       // [E][F][H] fp16 (swizzled), 2 MB
    _Float16* W2t = W1t + (size_t)E * F * H;               // [E][8][256][64] fp16 (swizzled), 2 MB
    float* probs  = (float*)(W2t + (size_t)E * H * F);     // [T][E] fp32, 1 MB

    dim3 tb(32, 8);
    prep_w1<<<dim3(F / 32, H / 32, E), tb, 0, stream>>>(W1, W1t);
    prep_w2<<<dim3(H / 32, F / 32, E), tb, 0, stream>>>(W2, W2t);
    gate_kernel<<<(T_TOK * E) / 256, 256, 0, stream>>>(x, Wg, bg, probs);
    moe_main<<<T_TOK / BM, 512, 0, stream>>>(x, W1t, b1, W2t, b2, probs, out);
}

// Round 5
// 226.040 us; speedup vs baseline: 1.4177x; 1.2890x over previous
//
#include <hip/hip_runtime.h>
#include <hip/hip_bf16.h>
#include <math.h>

#define H 256
#define F 512
#define E 8
#define T_TOK 32768
#define BM 128   // tokens per block
#define FC 64    // F-chunk size
#define NCH 64   // E * F/FC chunks

typedef float    f32x4 __attribute__((__ext_vector_type__(4)));
typedef _Float16 f16x8 __attribute__((__ext_vector_type__(8)));
typedef _Float16 f16x4 __attribute__((__ext_vector_type__(4)));

#define BAR_LG()  asm volatile("s_waitcnt lgkmcnt(0)\ns_barrier" ::: "memory")
#define BAR_ALL() asm volatile("s_waitcnt vmcnt(0) lgkmcnt(0)\ns_barrier" ::: "memory")

__device__ __forceinline__ void async_copy16(const void* g, void* l) {
    __builtin_amdgcn_global_load_lds((const __attribute__((address_space(1))) void*)g,
                                     (__attribute__((address_space(3))) void*)l, 16, 0, 0);
}

// gelu(v) = v - v * rcp(1 + exp2(v*(c1 + c2*v^2)))   [tanh-approx, ~7 ops]
__device__ __forceinline__ float gelu_fast(float v) {
    const float c1 = 2.302117236f;    // 2*0.7978845608*log2(e)
    const float c2 = 0.102943842f;    // 2*0.7978845608*0.044715*log2(e)
    float u2 = v * fmaf(c2, v * v, c1);
    float ex = __builtin_amdgcn_exp2f(u2);
    float r = __builtin_amdgcn_rcpf(ex + 1.0f);
    return v - v * r;
}

// W1[e][h][f] fp32 -> W1t[e][f][ h ^ ((f&7)<<3) ] fp16  (swizzle baked)
__global__ void prep_w1(const float* __restrict__ in, _Float16* __restrict__ out) {
    __shared__ float t[32][33];
    int e = blockIdx.z, f0 = blockIdx.x * 32, h0 = blockIdx.y * 32;
    int tx = threadIdx.x, ty = threadIdx.y;
    const float* ip = in + ((size_t)e * H + h0) * F + f0;
    for (int i = 0; i < 32; i += 8) t[ty + i][tx] = ip[(size_t)(ty + i) * F + tx]; // t[hl][fl]
    __syncthreads();
    _Float16* op = out + (size_t)e * F * H;
    for (int i = 0; i < 32; i += 8) {
        int f = f0 + ty + i, h = h0 + tx;
        op[(size_t)f * H + (h ^ ((f & 7) << 3))] = (_Float16)t[tx][ty + i];
    }
}

// W2[e][f][h] fp32 -> W2t[e][f>>6][h][ (f&63) ^ ((h&7)<<3) ] fp16  (64-f units, swizzle baked)
__global__ void prep_w2(const float* __restrict__ in, _Float16* __restrict__ out) {
    __shared__ float t[32][33];
    int e = blockIdx.z, h0 = blockIdx.x * 32, f0 = blockIdx.y * 32;
    int tx = threadIdx.x, ty = threadIdx.y;
    const float* ip = in + ((size_t)e * F + f0) * H + h0;
    for (int i = 0; i < 32; i += 8) t[ty + i][tx] = ip[(size_t)(ty + i) * H + tx]; // t[fl][hl]
    __syncthreads();
    _Float16* op = out + (size_t)e * 8 * 256 * 64;
    for (int i = 0; i < 32; i += 8) {
        int h = h0 + ty + i, f = f0 + tx;
        op[((size_t)(f >> 6) * 256 + h) * 64 + ((f & 63) ^ ((h & 7) << 3))] = (_Float16)t[tx][ty + i];
    }
}

__global__ void gate_kernel(const float* __restrict__ x, const float* __restrict__ Wg,
                            const float* __restrict__ bg, float* __restrict__ probs) {
    int gid = blockIdx.x * blockDim.x + threadIdx.x;
    int t = gid >> 3, e = gid & 7;
    const float* xr = x + (size_t)t * H;
    float acc = 0.f;
    for (int k = 0; k < H; k += 4) {
        float4 xv = *(const float4*)(xr + k);
        acc += xv.x * Wg[(k + 0) * E + e] + xv.y * Wg[(k + 1) * E + e]
             + xv.z * Wg[(k + 2) * E + e] + xv.w * Wg[(k + 3) * E + e];
    }
    acc += bg[e];
    float m = acc;
    for (int s = 1; s < 8; s <<= 1) m = fmaxf(m, __shfl_xor(m, s, 8));
    float p = expf(acc - m);
    float sum = p;
    for (int s = 1; s < 8; s <<= 1) sum += __shfl_xor(sum, s, 8);
    probs[gid] = p / sum;
}

// stage chunk s's W1 (32KB) + W2 (32KB) tiles: pure linear async copies (swizzle baked in prep)
__device__ __forceinline__ void stage_chunk(const _Float16* W1t, const _Float16* W2t,
                                            int s, _Float16* w1d, _Float16* w2d,
                                            int wid, int lane) {
    const char* w1src = (const char*)W1t + (size_t)s * 32768;
    const char* w2src = (const char*)W2t + (size_t)s * 32768;
#pragma unroll
    for (int q = 0; q < 4; ++q) {
        int o = (wid * 4 + q) * 1024 + lane * 16;
        async_copy16(w1src + o, (char*)w1d + o);
        async_copy16(w2src + o, (char*)w2d + o);
    }
}

// ---- main fused MoE FFN
__global__ __launch_bounds__(512, 2) void moe_main(
    const float* __restrict__ x, const _Float16* __restrict__ W1t,
    const float* __restrict__ b1, const _Float16* __restrict__ W2t,
    const float* __restrict__ b2, const float* __restrict__ probs,
    float* __restrict__ out) {

    __shared__ __align__(16) _Float16 w1s[2][FC * H];  // 2 x 32 KB
    __shared__ __align__(16) _Float16 w2s[2][H * FC];  // 2 x 32 KB
    __shared__ __align__(16) _Float16 hs[BM * FC];     // 16 KB

    int tid = threadIdx.x;
    int lane = tid & 63, wid = tid >> 6;
    int t0 = blockIdx.x * BM;
    int l15 = lane & 15, l4 = lane >> 4;

    // wave coords
    int fw = wid >> 2, tw1 = wid & 3;   // GEMM1: 2(f) x 4(tok), 2x2 16-tiles each
    int hw = wid >> 1, tw2 = wid & 1;   // GEMM2: 4(h) x 2(tok), 4x4 16-tiles each

    // x B-fragments in registers, loaded once, reused across all 64 chunks
    f16x8 xf[8][2];
#pragma unroll
    for (int j = 0; j < 2; ++j) {
        const float* xr = x + (size_t)(t0 + tw1 * 32 + j * 16 + l15) * H + (l4 << 3);
#pragma unroll
        for (int ks = 0; ks < 8; ++ks) {
            float4 v0 = *(const float4*)(xr + ks * 32);
            float4 v1 = *(const float4*)(xr + ks * 32 + 4);
            f16x8 hv;
            hv[0] = (_Float16)v0.x; hv[1] = (_Float16)v0.y; hv[2] = (_Float16)v0.z; hv[3] = (_Float16)v0.w;
            hv[4] = (_Float16)v1.x; hv[5] = (_Float16)v1.y; hv[6] = (_Float16)v1.z; hv[7] = (_Float16)v1.w;
            xf[ks][j] = hv;
        }
    }

    stage_chunk(W1t, W2t, 0, w1s[0], w2s[0], wid, lane);
    BAR_ALL();

    f32x4 yacc[4][4];
#pragma unroll
    for (int i = 0; i < 4; ++i)
#pragma unroll
        for (int j = 0; j < 4; ++j) yacc[i][j] = (f32x4){0.f, 0.f, 0.f, 0.f};

    for (int e = 0; e < E; ++e) {
        float pg0 = probs[(size_t)(t0 + tw1 * 32 + l15) * E + e];
        float pg1 = probs[(size_t)(t0 + tw1 * 32 + 16 + l15) * E + e];

        for (int c = 0; c < F / FC; ++c) {
            int s = e * 8 + c;
            int b = s & 1;
            int fbase = c * FC;
            const _Float16* w1p = w1s[b];
            const _Float16* w2p = w2s[b];

            // (1) prefetch next chunk (in flight until BAR_ALL; 1 chunk of slack)
            if (s + 1 < NCH)
                stage_chunk(W1t, W2t, s + 1, w1s[b ^ 1], w2s[b ^ 1], wid, lane);

            // (2) GEMM1: hT[f][tok], K=H (A from LDS baked-swizzle, B=x from regs)
            f32x4 hacc[2][2];
            hacc[0][0] = hacc[0][1] = hacc[1][0] = hacc[1][1] = (f32x4){0.f, 0.f, 0.f, 0.f};
            __builtin_amdgcn_s_setprio(1);
#pragma unroll
            for (int ks = 0; ks < 8; ++ks) {
                int kidx = ks * 32 + (l4 << 3);
                int fr0 = fw * 32 + l15, fr1 = fr0 + 16;
                f16x8 a0 = *(const f16x8*)&w1p[fr0 * H + (kidx ^ ((fr0 & 7) << 3))];
                f16x8 a1 = *(const f16x8*)&w1p[fr1 * H + (kidx ^ ((fr1 & 7) << 3))];
                hacc[0][0] = __builtin_amdgcn_mfma_f32_16x16x32_f16(a0, xf[ks][0], hacc[0][0], 0, 0, 0);
                hacc[0][1] = __builtin_amdgcn_mfma_f32_16x16x32_f16(a0, xf[ks][1], hacc[0][1], 0, 0, 0);
                hacc[1][0] = __builtin_amdgcn_mfma_f32_16x16x32_f16(a1, xf[ks][0], hacc[1][0], 0, 0, 0);
                hacc[1][1] = __builtin_amdgcn_mfma_f32_16x16x32_f16(a1, xf[ks][1], hacc[1][1], 0, 0, 0);
            }
            __builtin_amdgcn_s_setprio(0);

            // (3) GELU phase (VALU) + hs writes + HOISTED av reads (LDS) — pipes overlap here
            f16x8 av[4][2];
#pragma unroll
            for (int i = 0; i < 4; ++i) {
                int hr = hw * 64 + i * 16 + l15;
                int base = hr * FC;
                int sw = (hr & 7) << 3;
                av[i][0] = *(const f16x8*)&w2p[base + (((l4 << 3)) ^ sw)];
                av[i][1] = *(const f16x8*)&w2p[base + ((32 + (l4 << 3)) ^ sw)];
            }
#pragma unroll
            for (int i = 0; i < 2; ++i) {
                int flocal = (fw * 2 + i) * 16 + l4 * 4;
                float4 bv = *(const float4*)(b1 + (size_t)e * F + fbase + flocal);
#pragma unroll
                for (int j = 0; j < 2; ++j) {
                    int tokl = tw1 * 32 + j * 16 + l15;
                    float p = j ? pg1 : pg0;
                    f32x4 hv = hacc[i][j];
                    f16x4 hp;
                    hp[0] = (_Float16)(p * gelu_fast(hv[0] + bv.x));
                    hp[1] = (_Float16)(p * gelu_fast(hv[1] + bv.y));
                    hp[2] = (_Float16)(p * gelu_fast(hv[2] + bv.z));
                    hp[3] = (_Float16)(p * gelu_fast(hv[3] + bv.w));
                    int idx = (tokl * FC + flocal) ^ ((tokl & 7) << 3);
                    *(f16x4*)&hs[idx] = hp;
                }
            }
            BAR_LG();  // hs visible; W1/W2 prefetch stays in flight

            // (4) GEMM2: y[h][tok] += W2chunk . hs^T, K=FC (av already in regs)
            __builtin_amdgcn_s_setprio(1);
#pragma unroll
            for (int ks = 0; ks < FC / 32; ++ks) {
                int kidx = ks * 32 + (l4 << 3);
                f16x8 bv2[4];
#pragma unroll
                for (int j = 0; j < 4; ++j) {
                    int tok = tw2 * 64 + j * 16 + l15;
                    bv2[j] = *(const f16x8*)&hs[(tok * FC + kidx) ^ ((tok & 7) << 3)];
                }
#pragma unroll
                for (int i = 0; i < 4; ++i)
#pragma unroll
                    for (int j = 0; j < 4; ++j)
                        yacc[i][j] = __builtin_amdgcn_mfma_f32_16x16x32_f16(av[i][ks], bv2[j], yacc[i][j], 0, 0, 0);
            }
            __builtin_amdgcn_s_setprio(0);
            BAR_ALL();  // hs reads done + next chunk staged
        }
    }

    // epilogue: out = yacc + sum_e p_e * b2_e
#pragma unroll
    for (int j = 0; j < 4; ++j) {
        int tok = t0 + tw2 * 64 + j * 16 + l15;
        float pe[8];
#pragma unroll
        for (int e = 0; e < 8; ++e) pe[e] = probs[(size_t)tok * E + e];
#pragma unroll
        for (int i = 0; i < 4; ++i) {
            int h0 = hw * 64 + i * 16 + l4 * 4;
            f32x4 acc = yacc[i][j];
#pragma unroll
            for (int e = 0; e < 8; ++e) {
                float4 b2v = *(const float4*)(b2 + (size_t)e * H + h0);
                acc[0] += pe[e] * b2v.x;
                acc[1] += pe[e] * b2v.y;
                acc[2] += pe[e] * b2v.z;
                acc[3] += pe[e] * b2v.w;
            }
            *(f32x4*)(out + (size_t)tok * H + h0) = acc;
        }
    }
}

extern "C" void kernel_launch(void* const* d_in, const int* in_sizes, int n_in,
                              void* d_out, int out_size, void* d_ws, size_t ws_size,
                              hipStream_t stream) {
    const float* x  = (const float*)d_in[0];
    const float* Wg = (const float*)d_in[1];
    const float* bg = (const float*)d_in[2];
    const float* W1 = (const float*)d_in[3];
    const float* b1 = (const float*)d_in[4];
    const float* W2 = (const float*)d_in[5];
    const float* b2 = (const float*)d_in[6];
    float* out = (float*)d_out;

    _Float16* W1t = (_Float16*)d_ws;                       // [E][F][H] fp16 swizzled, 2 MB
    _Float16* W2t = W1t + (size_t)E * F * H;               // [E][8][256][64] fp16 swizzled, 2 MB
    float* probs  = (float*)(W2t + (size_t)E * H * F);     // [T][E] fp32, 1 MB

    dim3 tb(32, 8);
    prep_w1<<<dim3(F / 32, H / 32, E), tb, 0, stream>>>(W1, W1t);
    prep_w2<<<dim3(H / 32, F / 32, E), tb, 0, stream>>>(W2, W2t);
    gate_kernel<<<(T_TOK * E) / 256, 256, 0, stream>>>(x, Wg, bg, probs);
    moe_main<<<T_TOK / BM, 512, 0, stream>>>(x, W1t, b1, W2t, b2, probs, out);
}